// Round 1
// baseline (1524.750 us; speedup 1.0000x reference)
//
#include <hip/hip_runtime.h>
#include <cstdint>
#include <cstddef>

#define DIMD   2048
#define NEXP   32
#define TOPKK  4
#define INTERI 1024
#define TTOK   4096
#define NSLOT  (TTOK*TOPKK)   // 16384

typedef short bf16x8 __attribute__((ext_vector_type(8)));
typedef float f32x4  __attribute__((ext_vector_type(4)));

__device__ __forceinline__ unsigned short f2bf(float f){
  unsigned int u = __float_as_uint(f);
  u = (u + 0x7FFFu + ((u >> 16) & 1u)) >> 16;
  return (unsigned short)u;
}
__device__ __forceinline__ unsigned int pk2(float a, float b){
  return (unsigned int)f2bf(a) | ((unsigned int)f2bf(b) << 16);
}
__device__ __forceinline__ uint4 pack8(const float4& a, const float4& b){
  return make_uint4(pk2(a.x,a.y), pk2(a.z,a.w), pk2(b.x,b.y), pk2(b.z,b.w));
}

// ---------------- gate: softmax + top-4 ----------------
__global__ __launch_bounds__(64) void gate_kernel(
    const float* __restrict__ x, const float* __restrict__ gw,
    int* __restrict__ topk_i, float* __restrict__ topk_w, int* __restrict__ counts)
{
  int t = blockIdx.x;
  int lane = threadIdx.x;
  const float* xr = x + (size_t)t * DIMD;
  float xv[32];
  #pragma unroll
  for (int j = 0; j < 32; j++) xv[j] = xr[lane + 64*j];

  float myscore = -1e30f;
  for (int e = 0; e < NEXP; e++){
    const float* we = gw + (size_t)e * DIMD;
    float p = 0.f;
    #pragma unroll
    for (int j = 0; j < 32; j++) p += xv[j] * we[lane + 64*j];
    #pragma unroll
    for (int s = 32; s > 0; s >>= 1) p += __shfl_xor(p, s, 64);
    if (lane == e) myscore = p;
  }
  float v = (lane < NEXP) ? myscore : -1e30f;
  float m = v;
  #pragma unroll
  for (int s = 32; s > 0; s >>= 1) m = fmaxf(m, __shfl_xor(m, s, 64));
  float ev = (lane < NEXP) ? __expf(v - m) : 0.f;
  float ssum = ev;
  #pragma unroll
  for (int s = 32; s > 0; s >>= 1) ssum += __shfl_xor(ssum, s, 64);
  float prob = (lane < NEXP) ? (ev / ssum) : -1.f;

  float pcur = prob;
  for (int k = 0; k < TOPKK; k++){
    float bv = pcur; int bi = lane;
    #pragma unroll
    for (int s = 32; s > 0; s >>= 1){
      float ov = __shfl_xor(bv, s, 64);
      int   oi = __shfl_xor(bi, s, 64);
      if (ov > bv || (ov == bv && oi < bi)){ bv = ov; bi = oi; }
    }
    if (lane == 0){
      topk_i[t*TOPKK + k] = bi;
      topk_w[t*TOPKK + k] = bv;
      atomicAdd(&counts[bi], 1);
    }
    if (lane == bi) pcur = -1.f;
  }
}

// ---------------- scan: counts -> offsets, zero cursor ----------------
__global__ void scan_kernel(const int* __restrict__ counts, int* __restrict__ offsets,
                            int* __restrict__ cursor)
{
  if (threadIdx.x == 0){
    int acc = 0;
    for (int e = 0; e < NEXP; e++){ offsets[e] = acc; acc += counts[e]; }
    offsets[NEXP] = acc;
  }
  if (threadIdx.x < NEXP) cursor[threadIdx.x] = 0;
}

// ---------------- build slot lists ----------------
__global__ __launch_bounds__(256) void build_kernel(
    const int* __restrict__ topk_i, const float* __restrict__ topk_w,
    const int* __restrict__ offsets, int* __restrict__ cursor,
    int* __restrict__ slot_token, float* __restrict__ slot_w)
{
  int t = blockIdx.x * blockDim.x + threadIdx.x;
  if (t >= TTOK) return;
  for (int k = 0; k < TOPKK; k++){
    int e = topk_i[t*TOPKK + k];
    int pos = atomicAdd(&cursor[e], 1);
    int s = offsets[e] + pos;
    slot_token[s] = t;
    slot_w[s] = topk_w[t*TOPKK + k];
  }
}

// ---------------- fp32 -> bf16 convert ----------------
__global__ __launch_bounds__(256) void cvt_kernel(
    const float* __restrict__ x, unsigned short* __restrict__ xb, int n)
{
  int i = (blockIdx.x * blockDim.x + threadIdx.x) * 8;
  if (i >= n) return;
  const float4* p = (const float4*)(x + i);
  float4 a = p[0], b = p[1];
  *(uint4*)(xb + i) = pack8(a, b);
}

// ---------------- GEMM1 (dual B + silu*mul + route weight) ----------------
// C tile: BM=128 rows x BN=64 cols per matrix. K = DIMD. 256 threads, 4 waves 2x2.
#define BM  128
#define BN  64
#define BKG 64
#define LDA 72   // ushort stride = BK + 8 pad

__global__ __launch_bounds__(256) void gemm1_dual(
    const unsigned short* __restrict__ xb,
    const float* __restrict__ W1g, const float* __restrict__ W3g,
    const int* __restrict__ slot_token, const float* __restrict__ slot_w,
    const int* __restrict__ offsets,
    unsigned short* __restrict__ H, int Ncols, int routed)
{
  __shared__ unsigned short As[BM*LDA];
  __shared__ unsigned short Bs1[BN*LDA];
  __shared__ unsigned short Bs3[BN*LDA];
  __shared__ int   rowtok[BM];
  __shared__ float roww[BM];

  int e = blockIdx.z;
  int seg0, segn;
  const float *W1, *W3;
  if (routed){
    seg0 = offsets[e]; segn = offsets[e+1] - seg0;
    W1 = W1g + (size_t)e * INTERI * DIMD;
    W3 = W3g + (size_t)e * INTERI * DIMD;
  } else {
    seg0 = 0; segn = TTOK; W1 = W1g; W3 = W3g;
  }
  int m0 = blockIdx.y * BM;
  if (m0 >= segn) return;
  int rows = min(BM, segn - m0);
  int n0 = blockIdx.x * BN;
  int tid = threadIdx.x;

  if (tid < BM){
    int r = tid;
    if (r < rows){
      int g = seg0 + m0 + r;
      rowtok[r] = routed ? slot_token[g] : g;
      roww[r]   = routed ? slot_w[g] : 1.0f;
    } else { rowtok[r] = -1; roww[r] = 0.f; }
  }
  __syncthreads();

  f32x4 zz = {0.f, 0.f, 0.f, 0.f};
  f32x4 acc1[4][2], acc3[4][2];
  #pragma unroll
  for (int i = 0; i < 4; i++)
    #pragma unroll
    for (int j = 0; j < 2; j++){ acc1[i][j] = zz; acc3[i][j] = zz; }

  int wv = tid >> 6, lane = tid & 63;
  int wm = wv >> 1, wn = wv & 1;
  int l15 = lane & 15, quad = lane >> 4;

  int ar = tid >> 1, ac = (tid & 1) * 32;   // A: 2 thr/row, 32 bf16 each
  int br = tid >> 2, bc = (tid & 3) * 16;   // B: 4 thr/row, 16 fp32 each
  int tok = rowtok[ar];

  for (int k0 = 0; k0 < DIMD; k0 += BKG){
    uint4 av[4];
    av[0] = av[1] = av[2] = av[3] = make_uint4(0,0,0,0);
    if (tok >= 0){
      const uint4* p = (const uint4*)(xb + (size_t)tok * DIMD + k0 + ac);
      av[0] = p[0]; av[1] = p[1]; av[2] = p[2]; av[3] = p[3];
    }
    const float4* b1p = (const float4*)(W1 + (size_t)(n0 + br) * DIMD + k0 + bc);
    const float4* b3p = (const float4*)(W3 + (size_t)(n0 + br) * DIMD + k0 + bc);
    float4 b1v0 = b1p[0], b1v1 = b1p[1], b1v2 = b1p[2], b1v3 = b1p[3];
    float4 b3v0 = b3p[0], b3v1 = b3p[1], b3v2 = b3p[2], b3v3 = b3p[3];

    __syncthreads();  // previous iter's LDS reads done
    {
      uint4* aw = (uint4*)&As[ar*LDA + ac];
      aw[0] = av[0]; aw[1] = av[1]; aw[2] = av[2]; aw[3] = av[3];
      uint4* b1w = (uint4*)&Bs1[br*LDA + bc];
      b1w[0] = pack8(b1v0, b1v1); b1w[1] = pack8(b1v2, b1v3);
      uint4* b3w = (uint4*)&Bs3[br*LDA + bc];
      b3w[0] = pack8(b3v0, b3v1); b3w[1] = pack8(b3v2, b3v3);
    }
    __syncthreads();

    #pragma unroll
    for (int ks = 0; ks < 2; ks++){
      bf16x8 af[4];
      #pragma unroll
      for (int im = 0; im < 4; im++)
        af[im] = *(const bf16x8*)&As[(wm*64 + im*16 + l15)*LDA + ks*32 + quad*8];
      bf16x8 b1f[2], b3f[2];
      #pragma unroll
      for (int in = 0; in < 2; in++){
        b1f[in] = *(const bf16x8*)&Bs1[(wn*32 + in*16 + l15)*LDA + ks*32 + quad*8];
        b3f[in] = *(const bf16x8*)&Bs3[(wn*32 + in*16 + l15)*LDA + ks*32 + quad*8];
      }
      #pragma unroll
      for (int im = 0; im < 4; im++)
        #pragma unroll
        for (int in = 0; in < 2; in++){
          acc1[im][in] = __builtin_amdgcn_mfma_f32_16x16x32_bf16(af[im], b1f[in], acc1[im][in], 0, 0, 0);
          acc3[im][in] = __builtin_amdgcn_mfma_f32_16x16x32_bf16(af[im], b3f[in], acc3[im][in], 0, 0, 0);
        }
    }
  }

  // epilogue: h = silu(c1) * c3 * route_w, store bf16
  #pragma unroll
  for (int im = 0; im < 4; im++){
    #pragma unroll
    for (int in = 0; in < 2; in++){
      int col = n0 + wn*32 + in*16 + l15;
      #pragma unroll
      for (int reg = 0; reg < 4; reg++){
        int rr = wm*64 + im*16 + quad*4 + reg;
        if (rr < rows){
          float v1 = acc1[im][in][reg];
          float v3 = acc3[im][in][reg];
          float hv = (v1 / (1.f + __expf(-v1))) * v3 * roww[rr];
          H[(size_t)(seg0 + m0 + rr) * Ncols + col] = f2bf(hv);
        }
      }
    }
  }
}

// ---------------- GEMM2: out += H @ W2^T (atomic scatter for routed) ----------------
#define BN2 128
__global__ __launch_bounds__(256) void gemm2_kernel(
    const unsigned short* __restrict__ Hsrc, const float* __restrict__ W2g,
    const int* __restrict__ slot_token, const int* __restrict__ offsets,
    float* __restrict__ out, int Kd, int routed)
{
  __shared__ unsigned short As[BM*LDA];
  __shared__ unsigned short Bs[BN2*LDA];
  __shared__ int rowtok[BM];

  int e = blockIdx.z;
  int seg0, segn;
  const float* W2;
  if (routed){
    seg0 = offsets[e]; segn = offsets[e+1] - seg0;
    W2 = W2g + (size_t)e * DIMD * INTERI;
  } else {
    seg0 = 0; segn = TTOK; W2 = W2g;
  }
  int m0 = blockIdx.y * BM;
  if (m0 >= segn) return;
  int rows = min(BM, segn - m0);
  int n0 = blockIdx.x * BN2;
  int tid = threadIdx.x;

  if (tid < BM){
    int r = tid;
    rowtok[r] = (r < rows) ? (routed ? slot_token[seg0 + m0 + r] : (m0 + r)) : -1;
  }
  __syncthreads();

  f32x4 zz = {0.f,0.f,0.f,0.f};
  f32x4 acc[4][4];
  #pragma unroll
  for (int i = 0; i < 4; i++)
    #pragma unroll
    for (int j = 0; j < 4; j++) acc[i][j] = zz;

  int wv = tid >> 6, lane = tid & 63;
  int wm = wv >> 1, wn = wv & 1;
  int l15 = lane & 15, quad = lane >> 4;

  int ar = tid >> 1, ac = (tid & 1) * 32;  // A: 2 thr/row, 32 bf16
  int brr = tid >> 1, bc = (tid & 1) * 32; // B: 2 thr/row, 32 fp32
  bool aok = (ar < rows);

  for (int k0 = 0; k0 < Kd; k0 += BKG){
    uint4 av[4];
    av[0] = av[1] = av[2] = av[3] = make_uint4(0,0,0,0);
    if (aok){
      const uint4* p = (const uint4*)(Hsrc + (size_t)(seg0 + m0 + ar) * Kd + k0 + ac);
      av[0] = p[0]; av[1] = p[1]; av[2] = p[2]; av[3] = p[3];
    }
    const float4* bp = (const float4*)(W2 + (size_t)(n0 + brr) * Kd + k0 + bc);
    float4 bv0 = bp[0], bv1 = bp[1], bv2 = bp[2], bv3 = bp[3];
    float4 bv4 = bp[4], bv5 = bp[5], bv6 = bp[6], bv7 = bp[7];

    __syncthreads();
    {
      uint4* aw = (uint4*)&As[ar*LDA + ac];
      aw[0] = av[0]; aw[1] = av[1]; aw[2] = av[2]; aw[3] = av[3];
      uint4* bw = (uint4*)&Bs[brr*LDA + bc];
      bw[0] = pack8(bv0, bv1); bw[1] = pack8(bv2, bv3);
      bw[2] = pack8(bv4, bv5); bw[3] = pack8(bv6, bv7);
    }
    __syncthreads();

    #pragma unroll
    for (int ks = 0; ks < 2; ks++){
      bf16x8 af[4], bfr[4];
      #pragma unroll
      for (int im = 0; im < 4; im++)
        af[im] = *(const bf16x8*)&As[(wm*64 + im*16 + l15)*LDA + ks*32 + quad*8];
      #pragma unroll
      for (int in = 0; in < 4; in++)
        bfr[in] = *(const bf16x8*)&Bs[(wn*64 + in*16 + l15)*LDA + ks*32 + quad*8];
      #pragma unroll
      for (int im = 0; im < 4; im++)
        #pragma unroll
        for (int in = 0; in < 4; in++)
          acc[im][in] = __builtin_amdgcn_mfma_f32_16x16x32_bf16(af[im], bfr[in], acc[im][in], 0, 0, 0);
    }
  }

  #pragma unroll
  for (int im = 0; im < 4; im++){
    #pragma unroll
    for (int in = 0; in < 4; in++){
      int col = n0 + wn*64 + in*16 + l15;
      #pragma unroll
      for (int reg = 0; reg < 4; reg++){
        int rr = wm*64 + im*16 + quad*4 + reg;
        if (rr < rows){
          int orow = rowtok[rr];
          float v = acc[im][in][reg];
          if (routed) atomicAdd(&out[(size_t)orow * DIMD + col], v);
          else        out[(size_t)orow * DIMD + col] += v;
        }
      }
    }
  }
}

// ---------------- launch ----------------
extern "C" void kernel_launch(void* const* d_in, const int* in_sizes, int n_in,
                              void* d_out, int out_size, void* d_ws, size_t ws_size,
                              hipStream_t stream)
{
  const float* x      = (const float*)d_in[0];
  const float* gate_w = (const float*)d_in[1];
  const float* w1     = (const float*)d_in[2];
  const float* w2     = (const float*)d_in[3];
  const float* w3     = (const float*)d_in[4];
  const float* sw1    = (const float*)d_in[5];
  const float* sw2    = (const float*)d_in[6];
  const float* sw3    = (const float*)d_in[7];
  float* out = (float*)d_out;

  char* w = (char*)d_ws;
  unsigned short* xb = (unsigned short*)(w);                     // 16,777,216 B
  unsigned short* h  = (unsigned short*)(w + 16777216);          // 33,554,432 B
  unsigned short* h2 = (unsigned short*)(w + 50331648);          // 16,777,216 B
  int*   slot_token  = (int*)  (w + 67108864);                   // 65,536 B
  float* slot_w      = (float*)(w + 67174400);                   // 65,536 B
  int*   topk_i      = (int*)  (w + 67239936);                   // 65,536 B
  float* topk_w      = (float*)(w + 67305472);                   // 65,536 B
  int*   counts      = (int*)  (w + 67371008);                   // 128 B
  int*   cursor      = (int*)  (w + 67371136);                   // 128 B
  int*   offsets     = (int*)  (w + 67371264);                   // 132 B

  hipMemsetAsync(out, 0, (size_t)TTOK * DIMD * sizeof(float), stream);
  hipMemsetAsync(counts, 0, NEXP * sizeof(int), stream);

  gate_kernel<<<TTOK, 64, 0, stream>>>(x, gate_w, topk_i, topk_w, counts);
  scan_kernel<<<1, 64, 0, stream>>>(counts, offsets, cursor);
  build_kernel<<<TTOK/256, 256, 0, stream>>>(topk_i, topk_w, offsets, cursor, slot_token, slot_w);
  cvt_kernel<<<(TTOK*DIMD)/(256*8), 256, 0, stream>>>(x, xb, TTOK*DIMD);

  // routed expert FFN
  gemm1_dual<<<dim3(INTERI/BN, 32, NEXP), 256, 0, stream>>>(
      xb, w1, w3, slot_token, slot_w, offsets, h, INTERI, 1);
  gemm2_kernel<<<dim3(DIMD/BN2, 32, NEXP), 256, 0, stream>>>(
      h, w2, slot_token, offsets, out, INTERI, 1);

  // shared expert (dense)
  gemm1_dual<<<dim3(2*INTERI/BN, TTOK/BM, 1), 256, 0, stream>>>(
      xb, sw1, sw3, nullptr, nullptr, offsets, h2, 2*INTERI, 0);
  gemm2_kernel<<<dim3(DIMD/BN2, TTOK/BM, 1), 256, 0, stream>>>(
      h2, sw2, nullptr, offsets, out, 2*INTERI, 0);
}

// Round 2
// 1504.985 us; speedup vs baseline: 1.0131x; 1.0131x over previous
//
#include <hip/hip_runtime.h>
#include <cstdint>
#include <cstddef>

#define DIMD   2048
#define NEXP   32
#define TOPKK  4
#define INTERI 1024
#define TTOK   4096

typedef short bf16x8 __attribute__((ext_vector_type(8)));
typedef float f32x4  __attribute__((ext_vector_type(4)));
typedef unsigned int u32;

__device__ __forceinline__ unsigned short f2bf(float f){
  unsigned int u = __float_as_uint(f);
  u = (u + 0x7FFFu + ((u >> 16) & 1u)) >> 16;
  return (unsigned short)u;
}
__device__ __forceinline__ unsigned int pk2(float a, float b){
  return (unsigned int)f2bf(a) | ((unsigned int)f2bf(b) << 16);
}
__device__ __forceinline__ uint4 pack8(const float4& a, const float4& b){
  return make_uint4(pk2(a.x,a.y), pk2(a.z,a.w), pk2(b.x,b.y), pk2(b.z,b.w));
}

// async global->LDS, 16B per lane. LDS dest = wave-uniform base + lane*16.
__device__ __forceinline__ void gl_lds16(const void* g, void* l){
  __builtin_amdgcn_global_load_lds(
      (const __attribute__((address_space(1))) u32*)g,
      (__attribute__((address_space(3))) u32*)l, 16, 0, 0);
}

// ---------------- gate: softmax + top-4 ----------------
__global__ __launch_bounds__(64) void gate_kernel(
    const float* __restrict__ x, const float* __restrict__ gw,
    int* __restrict__ topk_i, float* __restrict__ topk_w, int* __restrict__ counts)
{
  int t = blockIdx.x;
  int lane = threadIdx.x;
  const float* xr = x + (size_t)t * DIMD;
  float xv[32];
  #pragma unroll
  for (int j = 0; j < 32; j++) xv[j] = xr[lane + 64*j];

  float myscore = -1e30f;
  for (int e = 0; e < NEXP; e++){
    const float* we = gw + (size_t)e * DIMD;
    float p = 0.f;
    #pragma unroll
    for (int j = 0; j < 32; j++) p += xv[j] * we[lane + 64*j];
    #pragma unroll
    for (int s = 32; s > 0; s >>= 1) p += __shfl_xor(p, s, 64);
    if (lane == e) myscore = p;
  }
  float v = (lane < NEXP) ? myscore : -1e30f;
  float m = v;
  #pragma unroll
  for (int s = 32; s > 0; s >>= 1) m = fmaxf(m, __shfl_xor(m, s, 64));
  float ev = (lane < NEXP) ? __expf(v - m) : 0.f;
  float ssum = ev;
  #pragma unroll
  for (int s = 32; s > 0; s >>= 1) ssum += __shfl_xor(ssum, s, 64);
  float prob = (lane < NEXP) ? (ev / ssum) : -1.f;

  float pcur = prob;
  for (int k = 0; k < TOPKK; k++){
    float bv = pcur; int bi = lane;
    #pragma unroll
    for (int s = 32; s > 0; s >>= 1){
      float ov = __shfl_xor(bv, s, 64);
      int   oi = __shfl_xor(bi, s, 64);
      if (ov > bv || (ov == bv && oi < bi)){ bv = ov; bi = oi; }
    }
    if (lane == 0){
      topk_i[t*TOPKK + k] = bi;
      topk_w[t*TOPKK + k] = bv;
      atomicAdd(&counts[bi], 1);
    }
    if (lane == bi) pcur = -1.f;
  }
}

__global__ void scan_kernel(const int* __restrict__ counts, int* __restrict__ offsets,
                            int* __restrict__ cursor)
{
  if (threadIdx.x == 0){
    int acc = 0;
    for (int e = 0; e < NEXP; e++){ offsets[e] = acc; acc += counts[e]; }
    offsets[NEXP] = acc;
  }
  if (threadIdx.x < NEXP) cursor[threadIdx.x] = 0;
}

__global__ __launch_bounds__(256) void build_kernel(
    const int* __restrict__ topk_i, const float* __restrict__ topk_w,
    const int* __restrict__ offsets, int* __restrict__ cursor,
    int* __restrict__ slot_token, float* __restrict__ slot_w)
{
  int t = blockIdx.x * blockDim.x + threadIdx.x;
  if (t >= TTOK) return;
  for (int k = 0; k < TOPKK; k++){
    int e = topk_i[t*TOPKK + k];
    int pos = atomicAdd(&cursor[e], 1);
    int s = offsets[e] + pos;
    slot_token[s] = t;
    slot_w[s] = topk_w[t*TOPKK + k];
  }
}

// ---------------- fp32 -> bf16 convert (8 elems/thread) ----------------
__global__ __launch_bounds__(256) void cvt_kernel(
    const float* __restrict__ src, unsigned short* __restrict__ dst, int n)
{
  int i = (blockIdx.x * blockDim.x + threadIdx.x) * 8;
  if (i >= n) return;
  const float4* p = (const float4*)(src + i);
  float4 a = p[0], b = p[1];
  *(uint4*)(dst + i) = pack8(a, b);
}

// =======================================================================
// GEMM1 dual: h = silu(x@W1^T) * (x@W3^T) * route_w   (bf16 out)
// Tile: 128M x 64N (x2 matrices), BK=64. LDS unpadded [row][64] bf16,
// XOR-swizzled 16B chunks (chunk ^= row&7). 4 waves, 2x2 quadrants.
// =======================================================================
template<bool WB16>
__global__ __launch_bounds__(256) void gemm1_v2(
    const unsigned short* __restrict__ xb,
    const void* __restrict__ W1g, const void* __restrict__ W3g,
    const int* __restrict__ slot_token, const float* __restrict__ slot_w,
    const int* __restrict__ offsets,
    unsigned short* __restrict__ H, int Ncols, int routed)
{
  __shared__ unsigned short As[128*64];
  __shared__ unsigned short Bs1[64*64];
  __shared__ unsigned short Bs3[64*64];
  __shared__ float roww[128];

  int e = blockIdx.z;
  int seg0, segn;
  if (routed){ seg0 = offsets[e]; segn = offsets[e+1] - seg0; }
  else       { seg0 = 0; segn = TTOK; }
  int m0 = blockIdx.y * 128;
  if (m0 >= segn) return;
  int rows = min(128, segn - m0);
  int n0 = blockIdx.x * 64;
  int tid = threadIdx.x, wv = tid >> 6, lane = tid & 63;

  size_t woff = routed ? (size_t)e * INTERI * DIMD : 0;
  const unsigned short* W1h = nullptr; const unsigned short* W3h = nullptr;
  const float* W1f = nullptr; const float* W3f = nullptr;
  if constexpr (WB16){
    W1h = (const unsigned short*)W1g + woff;
    W3h = (const unsigned short*)W3g + woff;
  } else {
    W1f = (const float*)W1g + woff;
    W3f = (const float*)W3g + woff;
  }

  if (tid < 128)
    roww[tid] = (tid < rows) ? (routed ? slot_w[seg0 + m0 + tid] : 1.0f) : 0.f;

  int sub = lane >> 3, cst = lane & 7;
  int swz = cst ^ sub;       // rows staged in groups of 8 => row&7 == sub

  // A bases: wave wv stages rows [wv*32, wv*32+32), 4 issues of 8 rows
  const unsigned short* agp[4];
  #pragma unroll
  for (int t = 0; t < 4; t++){
    int r = wv*32 + t*8 + sub;
    int rc = (r < rows) ? r : 0;
    int tok = routed ? slot_token[seg0 + m0 + rc] : (m0 + rc);
    agp[t] = xb + (size_t)tok * DIMD + swz*8;
  }
  // B bases (bf16 path): wave stages B1 rows [wv*16,+16), B3 same
  const unsigned short* bg1[2]; const unsigned short* bg3[2];
  if constexpr (WB16){
    #pragma unroll
    for (int t = 0; t < 2; t++){
      int r = wv*16 + t*8 + sub;
      bg1[t] = W1h + (size_t)(n0 + r) * DIMD + swz*8;
      bg3[t] = W3h + (size_t)(n0 + r) * DIMD + swz*8;
    }
  }

  f32x4 zz = {0.f,0.f,0.f,0.f};
  f32x4 acc1[4][2], acc3[4][2];
  #pragma unroll
  for (int i = 0; i < 4; i++)
    #pragma unroll
    for (int j = 0; j < 2; j++){ acc1[i][j] = zz; acc3[i][j] = zz; }

  int wm = wv >> 1, wn = wv & 1;
  int l15 = lane & 15, quad = lane >> 4;

  for (int k0 = 0; k0 < DIMD; k0 += 64){
    float4 v1a[2], v1b[2], v3a[2], v3b[2];
    if constexpr (!WB16){
      #pragma unroll
      for (int s = 0; s < 2; s++){
        int m = tid + s*256;           // 0..511 chunks (64 rows x 8)
        int r = m >> 3, c = m & 7;
        int clog = c ^ (r & 7);
        const float4* p1 = (const float4*)(W1f + (size_t)(n0 + r)*DIMD + k0 + clog*8);
        const float4* p3 = (const float4*)(W3f + (size_t)(n0 + r)*DIMD + k0 + clog*8);
        v1a[s] = p1[0]; v1b[s] = p1[1];
        v3a[s] = p3[0]; v3b[s] = p3[1];
      }
    }
    __syncthreads();   // prior iter's LDS reads done
    #pragma unroll
    for (int t = 0; t < 4; t++)
      gl_lds16(agp[t] + k0, &As[(wv*32 + t*8) * 64]);
    if constexpr (WB16){
      #pragma unroll
      for (int t = 0; t < 2; t++){
        gl_lds16(bg1[t] + k0, &Bs1[(wv*16 + t*8) * 64]);
        gl_lds16(bg3[t] + k0, &Bs3[(wv*16 + t*8) * 64]);
      }
    } else {
      #pragma unroll
      for (int s = 0; s < 2; s++){
        int m = tid + s*256;
        int r = m >> 3, c = m & 7;
        *(uint4*)&Bs1[r*64 + c*8] = pack8(v1a[s], v1b[s]);
        *(uint4*)&Bs3[r*64 + c*8] = pack8(v3a[s], v3b[s]);
      }
    }
    __syncthreads();   // staging (incl. async loads) drained

    #pragma unroll
    for (int ks = 0; ks < 2; ks++){
      bf16x8 af[4];
      #pragma unroll
      for (int im = 0; im < 4; im++){
        int row = wm*64 + im*16 + l15;
        int pc = (ks*4 + quad) ^ (l15 & 7);
        af[im] = *(const bf16x8*)&As[row*64 + pc*8];
      }
      bf16x8 b1f[2], b3f[2];
      #pragma unroll
      for (int in = 0; in < 2; in++){
        int row = wn*32 + in*16 + l15;
        int pc = (ks*4 + quad) ^ (l15 & 7);
        b1f[in] = *(const bf16x8*)&Bs1[row*64 + pc*8];
        b3f[in] = *(const bf16x8*)&Bs3[row*64 + pc*8];
      }
      #pragma unroll
      for (int im = 0; im < 4; im++)
        #pragma unroll
        for (int in = 0; in < 2; in++){
          acc1[im][in] = __builtin_amdgcn_mfma_f32_16x16x32_bf16(af[im], b1f[in], acc1[im][in], 0, 0, 0);
          acc3[im][in] = __builtin_amdgcn_mfma_f32_16x16x32_bf16(af[im], b3f[in], acc3[im][in], 0, 0, 0);
        }
    }
  }

  #pragma unroll
  for (int im = 0; im < 4; im++){
    #pragma unroll
    for (int in = 0; in < 2; in++){
      int col = n0 + wn*32 + in*16 + l15;
      #pragma unroll
      for (int reg = 0; reg < 4; reg++){
        int rr = wm*64 + im*16 + quad*4 + reg;
        if (rr < rows){
          float v1 = acc1[im][in][reg];
          float v3 = acc3[im][in][reg];
          float hv = (v1 / (1.f + __expf(-v1))) * v3 * roww[rr];
          H[(size_t)(seg0 + m0 + rr) * Ncols + col] = f2bf(hv);
        }
      }
    }
  }
}

// =======================================================================
// GEMM2: out = / += H @ W2^T. Tile 128M x 128N, BK=64. Same LDS scheme.
// routed: atomicAdd scatter by token; shared: plain store (runs first).
// =======================================================================
template<bool WB16>
__global__ __launch_bounds__(256) void gemm2_v2(
    const unsigned short* __restrict__ Hsrc, const void* __restrict__ W2g,
    const int* __restrict__ slot_token, const int* __restrict__ offsets,
    float* __restrict__ out, int Kd, int routed)
{
  __shared__ unsigned short As[128*64];
  __shared__ unsigned short Bs[128*64];
  __shared__ int rowtok[128];

  int e = blockIdx.z;
  int seg0, segn;
  if (routed){ seg0 = offsets[e]; segn = offsets[e+1] - seg0; }
  else       { seg0 = 0; segn = TTOK; }
  int m0 = blockIdx.y * 128;
  if (m0 >= segn) return;
  int rows = min(128, segn - m0);
  int n0 = blockIdx.x * 128;
  int tid = threadIdx.x, wv = tid >> 6, lane = tid & 63;

  size_t woff = routed ? (size_t)e * DIMD * INTERI : 0;
  const unsigned short* W2h = nullptr; const float* W2f = nullptr;
  if constexpr (WB16) W2h = (const unsigned short*)W2g + woff;
  else                W2f = (const float*)W2g + woff;

  if (tid < 128)
    rowtok[tid] = (tid < rows) ? (routed ? slot_token[seg0 + m0 + tid] : (m0 + tid)) : -1;

  int sub = lane >> 3, cst = lane & 7;
  int swz = cst ^ sub;

  const unsigned short* agp[4];
  #pragma unroll
  for (int t = 0; t < 4; t++){
    int r = wv*32 + t*8 + sub;
    int rc = (r < rows) ? r : 0;
    agp[t] = Hsrc + (size_t)(seg0 + m0 + rc) * Kd + swz*8;
  }
  const unsigned short* bgp[4];
  if constexpr (WB16){
    #pragma unroll
    for (int t = 0; t < 4; t++){
      int r = wv*32 + t*8 + sub;
      bgp[t] = W2h + (size_t)(n0 + r) * Kd + swz*8;
    }
  }

  f32x4 zz = {0.f,0.f,0.f,0.f};
  f32x4 acc[4][4];
  #pragma unroll
  for (int i = 0; i < 4; i++)
    #pragma unroll
    for (int j = 0; j < 4; j++) acc[i][j] = zz;

  int wm = wv >> 1, wn = wv & 1;
  int l15 = lane & 15, quad = lane >> 4;

  for (int k0 = 0; k0 < Kd; k0 += 64){
    float4 bva[4], bvb[4];
    if constexpr (!WB16){
      #pragma unroll
      for (int s = 0; s < 4; s++){
        int m = tid + s*256;           // 0..1023 chunks (128 rows x 8)
        int r = m >> 3, c = m & 7;
        int clog = c ^ (r & 7);
        const float4* p = (const float4*)(W2f + (size_t)(n0 + r)*Kd + k0 + clog*8);
        bva[s] = p[0]; bvb[s] = p[1];
      }
    }
    __syncthreads();
    #pragma unroll
    for (int t = 0; t < 4; t++)
      gl_lds16(agp[t] + k0, &As[(wv*32 + t*8) * 64]);
    if constexpr (WB16){
      #pragma unroll
      for (int t = 0; t < 4; t++)
        gl_lds16(bgp[t] + k0, &Bs[(wv*32 + t*8) * 64]);
    } else {
      #pragma unroll
      for (int s = 0; s < 4; s++){
        int m = tid + s*256;
        int r = m >> 3, c = m & 7;
        *(uint4*)&Bs[r*64 + c*8] = pack8(bva[s], bvb[s]);
      }
    }
    __syncthreads();

    #pragma unroll
    for (int ks = 0; ks < 2; ks++){
      bf16x8 af[4], bfr[4];
      #pragma unroll
      for (int im = 0; im < 4; im++){
        int row = wm*64 + im*16 + l15;
        int pc = (ks*4 + quad) ^ (l15 & 7);
        af[im] = *(const bf16x8*)&As[row*64 + pc*8];
      }
      #pragma unroll
      for (int in = 0; in < 4; in++){
        int row = wn*64 + in*16 + l15;
        int pc = (ks*4 + quad) ^ (l15 & 7);
        bfr[in] = *(const bf16x8*)&Bs[row*64 + pc*8];
      }
      #pragma unroll
      for (int im = 0; im < 4; im++)
        #pragma unroll
        for (int in = 0; in < 4; in++)
          acc[im][in] = __builtin_amdgcn_mfma_f32_16x16x32_bf16(af[im], bfr[in], acc[im][in], 0, 0, 0);
    }
  }

  #pragma unroll
  for (int im = 0; im < 4; im++){
    #pragma unroll
    for (int in = 0; in < 4; in++){
      int col = n0 + wn*64 + in*16 + l15;
      #pragma unroll
      for (int reg = 0; reg < 4; reg++){
        int rr = wm*64 + im*16 + quad*4 + reg;
        if (rr < rows){
          int orow = rowtok[rr];
          float v = acc[im][in][reg];
          if (routed) atomicAdd(&out[(size_t)orow * DIMD + col], v);
          else        out[(size_t)orow * DIMD + col] = v;
        }
      }
    }
  }
}

// ---------------- launch ----------------
extern "C" void kernel_launch(void* const* d_in, const int* in_sizes, int n_in,
                              void* d_out, int out_size, void* d_ws, size_t ws_size,
                              hipStream_t stream)
{
  const float* x      = (const float*)d_in[0];
  const float* gate_w = (const float*)d_in[1];
  const float* w1     = (const float*)d_in[2];
  const float* w2     = (const float*)d_in[3];
  const float* w3     = (const float*)d_in[4];
  const float* sw1    = (const float*)d_in[5];
  const float* sw2    = (const float*)d_in[6];
  const float* sw3    = (const float*)d_in[7];
  float* out = (float*)d_out;

  const size_t SZ_WE = (size_t)NEXP * INTERI * DIMD * 2;   // 134,217,728 per routed weight (bf16)
  const size_t SZ_SW = (size_t)2*INTERI * DIMD * 2;        // 8,388,608 per shared weight (bf16)
  const size_t SZ_XB = (size_t)TTOK * DIMD * 2;            // 16,777,216
  const size_t SZ_H  = (size_t)TTOK * TOPKK * INTERI * 2;  // 33,554,432
  const size_t META  = 1u << 20;
  const size_t NEED  = 3*SZ_WE + 3*SZ_SW + SZ_XB + SZ_H + META;  // ~457 MiB

  char* w = (char*)d_ws;
  bool big = (ws_size >= NEED);

  unsigned short *w1b=0, *w3b=0, *w2b=0, *sw1b=0, *sw3b=0, *sw2b=0, *xb, *h;
  char* meta;
  if (big){
    size_t o = 0;
    w1b  = (unsigned short*)(w + o); o += SZ_WE;
    w3b  = (unsigned short*)(w + o); o += SZ_WE;
    w2b  = (unsigned short*)(w + o); o += SZ_WE;
    sw1b = (unsigned short*)(w + o); o += SZ_SW;
    sw3b = (unsigned short*)(w + o); o += SZ_SW;
    sw2b = (unsigned short*)(w + o); o += SZ_SW;
    xb   = (unsigned short*)(w + o); o += SZ_XB;
    h    = (unsigned short*)(w + o); o += SZ_H;
    meta = w + o;
  } else {
    xb   = (unsigned short*)(w);
    h    = (unsigned short*)(w + SZ_XB);
    meta = w + SZ_XB + SZ_H;
  }
  int*   slot_token = (int*)  (meta);
  float* slot_w     = (float*)(meta + 65536);
  int*   topk_i     = (int*)  (meta + 131072);
  float* topk_w     = (float*)(meta + 196608);
  int*   counts     = (int*)  (meta + 262144);
  int*   cursor     = (int*)  (meta + 262272);
  int*   offsets    = (int*)  (meta + 262400);

  hipMemsetAsync(counts, 0, NEXP * sizeof(int), stream);

  gate_kernel<<<TTOK, 64, 0, stream>>>(x, gate_w, topk_i, topk_w, counts);
  scan_kernel<<<1, 64, 0, stream>>>(counts, offsets, cursor);
  build_kernel<<<TTOK/256, 256, 0, stream>>>(topk_i, topk_w, offsets, cursor, slot_token, slot_w);
  cvt_kernel<<<(TTOK*DIMD)/(256*8), 256, 0, stream>>>(x, xb, TTOK*DIMD);

  if (big){
    const int NWE = NEXP * INTERI * DIMD;   // 67,108,864
    const int NSW = 2*INTERI * DIMD;        // 4,194,304
    cvt_kernel<<<NWE/(256*8), 256, 0, stream>>>(w1,  w1b,  NWE);
    cvt_kernel<<<NWE/(256*8), 256, 0, stream>>>(w3,  w3b,  NWE);
    cvt_kernel<<<NWE/(256*8), 256, 0, stream>>>(w2,  w2b,  NWE);
    cvt_kernel<<<NSW/(256*8), 256, 0, stream>>>(sw1, sw1b, NSW);
    cvt_kernel<<<NSW/(256*8), 256, 0, stream>>>(sw3, sw3b, NSW);
    cvt_kernel<<<NSW/(256*8), 256, 0, stream>>>(sw2, sw2b, NSW);

    // shared expert first: gemm2 plain-stores -> no memset of out needed
    gemm1_v2<true><<<dim3(2*INTERI/64, TTOK/128, 1), 256, 0, stream>>>(
        xb, sw1b, sw3b, nullptr, nullptr, offsets, h, 2*INTERI, 0);
    gemm2_v2<true><<<dim3(DIMD/128, TTOK/128, 1), 256, 0, stream>>>(
        h, sw2b, nullptr, offsets, out, 2*INTERI, 0);
    // routed experts accumulate on top
    gemm1_v2<true><<<dim3(INTERI/64, 32, NEXP), 256, 0, stream>>>(
        xb, w1b, w3b, slot_token, slot_w, offsets, h, INTERI, 1);
    gemm2_v2<true><<<dim3(DIMD/128, 32, NEXP), 256, 0, stream>>>(
        h, w2b, slot_token, offsets, out, INTERI, 1);
  } else {
    gemm1_v2<false><<<dim3(2*INTERI/64, TTOK/128, 1), 256, 0, stream>>>(
        xb, sw1, sw3, nullptr, nullptr, offsets, h, 2*INTERI, 0);
    gemm2_v2<false><<<dim3(DIMD/128, TTOK/128, 1), 256, 0, stream>>>(
        h, sw2, nullptr, offsets, out, 2*INTERI, 0);
    gemm1_v2<false><<<dim3(INTERI/64, 32, NEXP), 256, 0, stream>>>(
        xb, w1, w3, slot_token, slot_w, offsets, h, INTERI, 1);
    gemm2_v2<false><<<dim3(DIMD/128, 32, NEXP), 256, 0, stream>>>(
        h, w2, slot_token, offsets, out, INTERI, 1);
  }
}